// Round 17
// baseline (976.524 us; speedup 1.0000x reference)
//
#include <hip/hip_runtime.h>

// SPINN v17 = v16 (MFMA champion) + (1) fragment-major LDS operand layout
// opB[block][slot^=r XOR (block&15)][8] -> B-frag ds_read_b128 is contiguous
// 256B/quarter (2-way free) instead of 8-way conflicted; (2) provenance-split
// MFMA: seq-sourced operand regions (rows written by shift steps are bitwise
// seq) are staged pre-waitA with plain loads and their MFMA ks run BEFORE
// waitA (tracking 34/50 ks, tree 16/32 ks on reduce steps) -> tg published
// earlier, barrier-B exposure cut. waitA unconditional (R13/R14 invariant).

typedef _Float16 f16;
typedef f16 f16x8 __attribute__((ext_vector_type(8)));
typedef float f32x4 __attribute__((ext_vector_type(4)));

constexpr int NB  = 128;
constexpr int LL  = 32;
constexpr int TT  = 63;
constexpr int NWG = 256;
constexpr int NTH = 512;
constexpr int SROWS = 64;

struct Params {
  const float* seq; const int* trans;
  const float* Wx[4];              // i,o,f,u ; Wx[2]==W_o (ref bug kept)
  const float* Ul[4]; const float* Ur[4];
  const float* bias[4];            // b_i, b_o, b_f, b_u
  const float* tWih; const float* tWhh; const float* tbih; const float* tbhh;
  const float* th0; const float* tc0;
  float* stack; float* tg;
  f16* wU; f16* wT;
  unsigned* bm;
  float* out;
};

__device__ __forceinline__ float sigm(float x) { return 1.0f / (1.0f + __expf(-x)); }
__device__ __forceinline__ float tanh_f(float x) {
  x = fminf(fmaxf(x, -15.0f), 15.0f);
  float e = __expf(2.0f * x);
  return (e - 1.0f) / (e + 1.0f);
}
__device__ __forceinline__ float cohLoad(const float* a) {
  return __hip_atomic_load(const_cast<float*>(a), __ATOMIC_RELAXED, __HIP_MEMORY_SCOPE_AGENT);
}
__device__ __forceinline__ float4 cohLoad4(const float* a) {
  union { unsigned long long u[2]; float4 f; } r;
  const unsigned long long* p64 = (const unsigned long long*)a;
  r.u[0] = __hip_atomic_load(const_cast<unsigned long long*>(p64),
                             __ATOMIC_RELAXED, __HIP_MEMORY_SCOPE_AGENT);
  r.u[1] = __hip_atomic_load(const_cast<unsigned long long*>(p64 + 1),
                             __ATOMIC_RELAXED, __HIP_MEMORY_SCOPE_AGENT);
  return r.f;
}
__device__ __forceinline__ void cohStore(float* a, float v) {
  __hip_atomic_store(a, v, __ATOMIC_RELAXED, __HIP_MEMORY_SCOPE_AGENT);
}
__device__ __forceinline__ void cohStore2(float* a, float2 v) {
  union { float2 f; unsigned long long u; } r; r.f = v;
  __hip_atomic_store((unsigned long long*)a, r.u, __ATOMIC_RELAXED,
                     __HIP_MEMORY_SCOPE_AGENT);
}
__device__ __forceinline__ void drainvm() {
  asm volatile("s_waitcnt vmcnt(0)" ::: "memory");
}
__device__ __forceinline__ unsigned relAdd(unsigned* a) {
  return __hip_atomic_fetch_add(a, 1u, __ATOMIC_RELAXED, __HIP_MEMORY_SCOPE_AGENT) + 1u;
}
__device__ __forceinline__ void flagMax(unsigned* f, unsigned gen) {
  __hip_atomic_fetch_max(f, gen, __ATOMIC_RELAXED, __HIP_MEMORY_SCOPE_AGENT);
}
__device__ __forceinline__ void bar_arrive_any(unsigned* blk, unsigned gen, int l) {
  unsigned a = relAdd(blk + (l & 3) * 32);
  if (a == gen * 8u) {
    unsigned r = relAdd(blk + 128);
    if (r == gen * 4u) flagMax(blk + 160, gen);
  }
}
__device__ __forceinline__ void barA_arrive(unsigned* blk, unsigned gen, int l) {
  if (threadIdx.x == 0) bar_arrive_any(blk, gen, l);
}
__device__ __forceinline__ void bar_wait(unsigned* blk, unsigned gen) {
  if (threadIdx.x == 0) {
    while (__hip_atomic_load(blk + 160, __ATOMIC_RELAXED, __HIP_MEMORY_SCOPE_AGENT) < gen)
      __builtin_amdgcn_s_sleep(1);
  }
  __syncthreads();
}

__launch_bounds__(NTH)
__global__ void spinn_kernel(Params p) {
  const int w = blockIdx.x;
  const int t = threadIdx.x;
  const int cg  = w & 31;
  const int bgp = w >> 5;
  const int b0  = bgp * 16;
  const int nc0 = cg * 16;
  const int o0  = cg * 8;

  unsigned* blkA = p.bm + (size_t)bgp * 512;
  unsigned* blkB = blkA + 256;
  f16* wUcg = p.wU + (size_t)cg * 65536;   // [g][ks][lane][8]
  f16* wTcg = p.wT + (size_t)cg * 25600;   // [ks][lane][8]

  // fragment-major operand store: k-blocks 0..63 buf, 64..191 sp1|sp2, 192..199 th
  __shared__ f16   opB[200][16][8];
  __shared__ float th2s[16][68];
  __shared__ float tc2s[16][68];
  __shared__ float accR[64][17];
  __shared__ float xS[64][17];
  __shared__ float tbsum[256];
  __shared__ float biasS[4][16];
  __shared__ unsigned char sp1t[TT + 1][16], sp2t[TT + 1][16];
  __shared__ unsigned char sp1sr[TT + 1][16], sp2sr[TT + 1][16]; // <32 seq, 32 zero, 200 stack
  __shared__ unsigned char buft[TT + 1][16], redt[TT + 1][16];
  __shared__ int anyredt[TT + 1];
  __shared__ int bufSamet[TT + 1];
  __shared__ int s1preT[TT + 1], s2preT[TT + 1];
  __shared__ unsigned char rowSrcS[16][64];
  __shared__ unsigned char qstkS[16][40];

  const int rq = t >> 7;
  const int kb = (t & 127) * 4;

  auto wr4 = [&](int block, int r, float4 v) {
    union { f16 h[4]; uint2 u; } x;
    x.h[0] = (f16)v.x; x.h[1] = (f16)v.y; x.h[2] = (f16)v.z; x.h[3] = (f16)v.w;
    *(uint2*)&opB[block][r ^ (block & 15)][kb & 7] = x.u;
  };
  auto rdf = [&](int block, int m15) -> f16x8 {
    return *(const f16x8*)&opB[block][m15 ^ (block & 15)][0];
  };

  // ---- prologue: scalars / state
  if (t < 256) tbsum[t] = p.tbih[t] + p.tbhh[t];
  if (t < 64) biasS[t >> 4][t & 15] = p.bias[t >> 4][nc0 + (t & 15)];
  for (int i = t; i < 1024; i += NTH) {
    int b = i >> 6, j = i & 63;
    float h0 = p.th0[(size_t)(b0 + b) * 64 + j];
    th2s[b][j] = h0;
    tc2s[b][j] = p.tc0[(size_t)(b0 + b) * 64 + j];
    int blkTh = 192 + (j >> 3);
    opB[blkTh][b ^ (blkTh & 15)][j & 7] = (f16)h0;
  }
  // ---- prologue: weight conversion to f16 fragment order (own cg slice)
  for (int s = t; s < 8192; s += NTH) {             // tree: (g, ks, lane)
    int g = s >> 11, ks = (s >> 6) & 31, l = s & 63;
    int m = l & 15, hi = l >> 4;
    f16x8 v;
    #pragma unroll
    for (int i = 0; i < 8; ++i) {
      int k = ks * 32 + hi * 8 + i;
      const float* U = (k < 512) ? p.Ul[g] : p.Ur[g];
      v[i] = (f16)U[(size_t)(nc0 + m) * 512 + (k & 511)];
    }
    *(f16x8*)(wUcg + (size_t)s * 8) = v;
  }
  for (int s = t; s < 3200; s += NTH) {             // tracking: (ks, lane)
    int ks = s >> 6, l = s & 63;
    int m = l & 15, hi = l >> 4;
    f16x8 v = {(f16)0, (f16)0, (f16)0, (f16)0, (f16)0, (f16)0, (f16)0, (f16)0};
    if (m < 8) {
      int row = o0 + m;
      #pragma unroll
      for (int i = 0; i < 8; ++i) {
        int k = ks * 32 + hi * 8 + i;
        v[i] = (f16)((k < 1536) ? p.tWih[(size_t)row * 1536 + k]
                                : p.tWhh[(size_t)row * 64 + (k - 1536)]);
      }
    }
    *(f16x8*)(wTcg + (size_t)s * 8) = v;
  }
  // ---- prologue: schedule sim with provenance for our 16 b
  if (t < 16) {
    buft[0][t] = 255;
    rowSrcS[t][0] = 32;                     // row 0 = zeros
    int bl = t, qn = 0, bp = 0;
    for (int s = 1; s <= TT; ++s) {
      int mask = p.trans[(size_t)(b0 + bl) * TT + (s - 1)];
      int s1 = (qn >= 1) ? qstkS[bl][qn - 1] : 0;
      int s2 = (qn >= 2) ? qstkS[bl][qn - 2] : 0;
      int rd = (mask == 1);
      sp1t[s][bl] = (unsigned char)s1;
      sp2t[s][bl] = (unsigned char)s2;
      sp1sr[s][bl] = rowSrcS[bl][s1];
      sp2sr[s][bl] = rowSrcS[bl][s2];
      redt[s][bl] = (unsigned char)rd;
      int bfv = (bp < LL) ? bp : LL;
      buft[s][bl] = (unsigned char)bfv;
      rowSrcS[bl][s] = rd ? 200 : (unsigned char)((bfv < LL) ? bfv : 32);
      int qn2 = rd ? (qn - 2) : qn;
      qstkS[bl][qn2] = (unsigned char)s;
      qn = qn2 + 1;
      bp += rd ? 0 : 1;
    }
  }
  __syncthreads();
  if (t == 0) {
    for (int s = 1; s <= TT; ++s) {
      int a = 0, same = 1, p1 = 1, p2 = 1;
      for (int bl = 0; bl < 16; ++bl) {
        a |= redt[s][bl];
        same &= (buft[s][bl] == buft[s - 1][bl]);
        p1 &= (sp1sr[s][bl] <= 32);
        p2 &= (sp2sr[s][bl] <= 32);
      }
      anyredt[s] = a;
      bufSamet[s] = same;
      s1preT[s] = p1;
      s2preT[s] = p2;
    }
  }
  // zero our 32-col slice of stack row 0 for our 16 b
  {
    int bl = t >> 5, cc = t & 31;
    int col = (cc < 16) ? (nc0 + cc) : (512 + nc0 + (cc - 16));
    cohStore(p.stack + ((size_t)(b0 + bl) * SROWS) * 1024 + col, 0.0f);
  }
  drainvm();
  __syncthreads();
  unsigned genA = 1, genB = 0;
  barA_arrive(blkA, genA, cg);

  for (int step = 1; step <= TT; ++step) {
    const int anyred = anyredt[step];
    const int s1p = s1preT[step], s2p = s2preT[step];
    const unsigned gB = ++genB;
    const unsigned gAw = genA, gAn = genA + 1;
    const float4 z4 = make_float4(0.f, 0.f, 0.f, 0.f);

    // ---- pre-wait staging: buf (if changed) + seq/zero-sourced sp rows
    if (!bufSamet[step]) {
      #pragma unroll
      for (int i = 0; i < 4; ++i) {
        const int r = i * 4 + rq;
        const int bx = buft[step][r];
        float4 v = z4;
        if (bx < LL) v = *(const float4*)(p.seq + ((size_t)(b0 + r) * LL + bx) * 1024 + kb);
        wr4(kb >> 3, r, v);
      }
    }
    #pragma unroll
    for (int i = 0; i < 4; ++i) {
      const int r = i * 4 + rq;
      const int s1 = sp1sr[step][r], s2 = sp2sr[step][r];
      if (s1 <= 32) {
        float4 v = (s1 < LL) ? *(const float4*)(p.seq + ((size_t)(b0 + r) * LL + s1) * 1024 + kb) : z4;
        wr4(64 + (kb >> 3), r, v);
      }
      if (s2 <= 32) {
        float4 v = (s2 < LL) ? *(const float4*)(p.seq + ((size_t)(b0 + r) * LL + s2) * 1024 + kb) : z4;
        wr4(128 + (kb >> 3), r, v);
      }
    }
    // ---- pre-wait: shift steps write stack row from seq directly (fp32)
    if (!anyred && t < 128) {
      const int bl = t >> 3, nf = (t & 7) * 2, na = nc0 + nf;
      const int bx = buft[step][bl];
      float2 h2 = make_float2(0.f, 0.f), c2 = make_float2(0.f, 0.f);
      if (bx < LL) {
        const float* sb = p.seq + ((size_t)(b0 + bl) * LL + bx) * 1024;
        h2 = *(const float2*)(sb + na);
        c2 = *(const float2*)(sb + 512 + na);
      }
      float* sr = p.stack + ((size_t)(b0 + bl) * SROWS + step) * 1024;
      cohStore2(sr + na, h2);
      cohStore2(sr + 512 + na, c2);
    }
    float bhv = 0.f, bcv = 0.f, clv = 0.f, crv = 0.f;
    if (anyred && t < 256) {
      const int n = t & 15, bl = t >> 4, na = nc0 + n;
      int bx = buft[step][bl];
      if (bx < LL) {
        bhv = p.seq[((size_t)(b0 + bl) * LL + bx) * 1024 + na];
        bcv = p.seq[((size_t)(b0 + bl) * LL + bx) * 1024 + 512 + na];
      }
    }
    __syncthreads();                     // S1: pre-stage visible

    // ---- pre-waitA MFMAs on provenance-known regions
    const int lane = t & 63, m15 = lane & 15, hi = lane >> 4;
    f32x4 acc = {0.f, 0.f, 0.f, 0.f};
    if (t < 256) {
      if (anyred) {
        const int g = t >> 6;
        const f16* aBase = wUcg + (size_t)g * 32 * 512;
        if (s1p) {
          #pragma unroll 4
          for (int ks = 0; ks < 16; ++ks) {
            f16x8 a = *(const f16x8*)(aBase + ((size_t)ks * 64 + lane) * 8);
            acc = __builtin_amdgcn_mfma_f32_16x16x32_f16(a, rdf(64 + ks * 4 + hi, m15), acc, 0, 0, 0);
          }
        }
        if (s2p) {
          #pragma unroll 4
          for (int ks = 16; ks < 32; ++ks) {
            f16x8 a = *(const f16x8*)(aBase + ((size_t)ks * 64 + lane) * 8);
            acc = __builtin_amdgcn_mfma_f32_16x16x32_f16(a, rdf(64 + ks * 4 + hi, m15), acc, 0, 0, 0);
          }
        }
      }
    } else if (t >= 448) {
      #pragma unroll 4
      for (int ks = 0; ks < 16; ++ks) {   // buf
        f16x8 a = *(const f16x8*)(wTcg + ((size_t)ks * 64 + lane) * 8);
        acc = __builtin_amdgcn_mfma_f32_16x16x32_f16(a, rdf(ks * 4 + hi, m15), acc, 0, 0, 0);
      }
      if (s1p) {
        #pragma unroll 4
        for (int ks = 16; ks < 32; ++ks) {
          f16x8 a = *(const f16x8*)(wTcg + ((size_t)ks * 64 + lane) * 8);
          acc = __builtin_amdgcn_mfma_f32_16x16x32_f16(a, rdf(ks * 4 + hi, m15), acc, 0, 0, 0);
        }
      }
      if (s2p) {
        #pragma unroll 4
        for (int ks = 32; ks < 48; ++ks) {
          f16x8 a = *(const f16x8*)(wTcg + ((size_t)ks * 64 + lane) * 8);
          acc = __builtin_amdgcn_mfma_f32_16x16x32_f16(a, rdf(ks * 4 + hi, m15), acc, 0, 0, 0);
        }
      }
      #pragma unroll
      for (int ks = 48; ks < 50; ++ks) {  // th
        f16x8 a = *(const f16x8*)(wTcg + ((size_t)ks * 64 + lane) * 8);
        acc = __builtin_amdgcn_mfma_f32_16x16x32_f16(a, rdf(ks * 4 + hi, m15), acc, 0, 0, 0);
      }
    }
    bar_wait(blkA, gAw);                 // prev-step stack rows visible

    // ---- post-wait staging: stack-sourced rows (coherent from IC)
    #pragma unroll
    for (int i = 0; i < 4; ++i) {
      const int r = i * 4 + rq;
      if (sp1sr[step][r] == 200)
        wr4(64 + (kb >> 3), r,
            cohLoad4(p.stack + ((size_t)(b0 + r) * SROWS + sp1t[step][r]) * 1024 + kb));
      if (sp2sr[step][r] == 200)
        wr4(128 + (kb >> 3), r,
            cohLoad4(p.stack + ((size_t)(b0 + r) * SROWS + sp2t[step][r]) * 1024 + kb));
    }
    if (anyred && t < 256) {
      const int n = t & 15, bl = t >> 4, na = nc0 + n;
      clv = cohLoad(p.stack + ((size_t)(b0 + bl) * SROWS + sp1t[step][bl]) * 1024 + 512 + na);
      crv = cohLoad(p.stack + ((size_t)(b0 + bl) * SROWS + sp2t[step][bl]) * 1024 + 512 + na);
    }
    if (!anyred) drainvm();
    __syncthreads();                     // S3: post-stage visible
    if (!anyred) barA_arrive(blkA, gAn, cg);   // EARLY (after wait: safe)

    // ---- post-waitA MFMAs (remaining ks) + publish
    if (t < 256) {
      if (anyred) {
        const int g = t >> 6;
        const f16* aBase = wUcg + (size_t)g * 32 * 512;
        if (!s1p) {
          #pragma unroll 4
          for (int ks = 0; ks < 16; ++ks) {
            f16x8 a = *(const f16x8*)(aBase + ((size_t)ks * 64 + lane) * 8);
            acc = __builtin_amdgcn_mfma_f32_16x16x32_f16(a, rdf(64 + ks * 4 + hi, m15), acc, 0, 0, 0);
          }
        }
        if (!s2p) {
          #pragma unroll 4
          for (int ks = 16; ks < 32; ++ks) {
            f16x8 a = *(const f16x8*)(aBase + ((size_t)ks * 64 + lane) * 8);
            acc = __builtin_amdgcn_mfma_f32_16x16x32_f16(a, rdf(64 + ks * 4 + hi, m15), acc, 0, 0, 0);
          }
        }
        #pragma unroll
        for (int r = 0; r < 4; ++r)
          accR[(t >> 6) * 16 + hi * 4 + r][m15] = acc[r];
      }
    } else if (t >= 448) {
      if (!s1p) {
        #pragma unroll 4
        for (int ks = 16; ks < 32; ++ks) {
          f16x8 a = *(const f16x8*)(wTcg + ((size_t)ks * 64 + lane) * 8);
          acc = __builtin_amdgcn_mfma_f32_16x16x32_f16(a, rdf(ks * 4 + hi, m15), acc, 0, 0, 0);
        }
      }
      if (!s2p) {
        #pragma unroll 4
        for (int ks = 32; ks < 48; ++ks) {
          f16x8 a = *(const f16x8*)(wTcg + ((size_t)ks * 64 + lane) * 8);
          acc = __builtin_amdgcn_mfma_f32_16x16x32_f16(a, rdf(ks * 4 + hi, m15), acc, 0, 0, 0);
        }
      }
      if (hi < 2) {
        #pragma unroll
        for (int r = 0; r < 4; ++r)
          cohStore(p.tg + (size_t)(b0 + m15) * 256 + o0 + hi * 4 + r, acc[r]);
      }
      drainvm();
      if (lane == 0) bar_arrive_any(blkB, gB, cg);   // EARLY per-WG arrival
    }
    bar_wait(blkB, gB);                  // tg of whole set visible

    // ---- tracking LSTM elementwise (16 b x 64 j; tg loads up-front)
    {
      float gi[2], gf[2], gg[2], go[2];
      int bbp[2], jjp[2];
      #pragma unroll
      for (int rep = 0; rep < 2; ++rep) {
        const int it = t + rep * 512;
        bbp[rep] = it >> 6; jjp[rep] = it & 63;
        const float* tgb = p.tg + (size_t)(b0 + bbp[rep]) * 256;
        gi[rep] = cohLoad(tgb + jjp[rep]);
        gf[rep] = cohLoad(tgb + 64 + jjp[rep]);
        gg[rep] = cohLoad(tgb + 128 + jjp[rep]);
        go[rep] = cohLoad(tgb + 192 + jjp[rep]);
      }
      #pragma unroll
      for (int rep = 0; rep < 2; ++rep) {
        const int b = bbp[rep], j = jjp[rep];
        float c2 = sigm(gf[rep] + tbsum[64 + j]) * tc2s[b][j]
                 + sigm(gi[rep] + tbsum[j]) * tanh_f(gg[rep] + tbsum[128 + j]);
        float h2 = sigm(go[rep] + tbsum[192 + j]) * tanh_f(c2);
        tc2s[b][j] = c2;
        th2s[b][j] = h2;
        int blkTh = 192 + (j >> 3);
        opB[blkTh][b ^ (blkTh & 15)][j & 7] = (f16)h2;
      }
    }
    if (anyred) {
      __syncthreads();
      // x@W: 64 cc x 16 b, K=64 (fp32 VALU, weights L2-hot)
      #pragma unroll
      for (int rep = 0; rep < 2; ++rep) {
        const int it = t + rep * 512;
        const int cc = it >> 4, bl = it & 15;
        const float* wr = p.Wx[cc >> 4] + (size_t)(nc0 + (cc & 15)) * 64;
        float x = 0.f;
        #pragma unroll 4
        for (int j4 = 0; j4 < 64; j4 += 4) {
          float4 wv = *(const float4*)(wr + j4);
          float4 xv = *(const float4*)&th2s[bl][j4];
          x += wv.x*xv.x + wv.y*xv.y + wv.z*xv.z + wv.w*xv.w;
        }
        xS[cc][bl] = x;
      }
      __syncthreads();
      // gates + stack row write
      if (t < 256) {
        const int n = t & 15, bl = t >> 4, na = nc0 + n;
        float h, c;
        if (redt[step][bl]) {
          float pre[4];
          #pragma unroll
          for (int g = 0; g < 4; ++g) {
            const int cc = g * 16 + n;
            pre[g] = accR[cc][bl] + xS[cc][bl] + biasS[g][n];
          }
          float iv = sigm(pre[0]), ov = sigm(pre[1]);
          float fv = sigm(pre[2]), uv = tanh_f(pre[3]);
          c = iv * uv + fv * (clv + crv);
          h = ov * tanh_f(c);
        } else { h = bhv; c = bcv; }
        float* sr = p.stack + ((size_t)(b0 + bl) * SROWS + step) * 1024;
        cohStore(sr + na, h);
        cohStore(sr + 512 + na, c);
        if (step == TT) p.out[(size_t)(b0 + bl) * 512 + na] = h;
        drainvm();
      }
      __syncthreads();
      barA_arrive(blkA, gAn, cg);
    }
    genA = gAn;
  }
}

extern "C" void kernel_launch(void* const* d_in, const int* in_sizes, int n_in,
                              void* d_out, int out_size, void* d_ws, size_t ws_size,
                              hipStream_t stream) {
  Params p;
  p.seq   = (const float*)d_in[0];
  p.trans = (const int*)d_in[1];
  p.Wx[0] = (const float*)d_in[2];   // W_i
  p.Wx[1] = (const float*)d_in[4];   // W_o
  p.Wx[2] = (const float*)d_in[4];   // W_o  (ref bug: f-gate uses W_o)
  p.Wx[3] = (const float*)d_in[5];   // W_u
  p.Ul[0] = (const float*)d_in[6];  p.Ur[0] = (const float*)d_in[7];    // i
  p.Ul[1] = (const float*)d_in[10]; p.Ur[1] = (const float*)d_in[11];   // o
  p.Ul[2] = (const float*)d_in[8];  p.Ur[2] = (const float*)d_in[9];    // f
  p.Ul[3] = (const float*)d_in[12]; p.Ur[3] = (const float*)d_in[13];   // u
  p.bias[0] = (const float*)d_in[14];  // b_i
  p.bias[1] = (const float*)d_in[16];  // b_o
  p.bias[2] = (const float*)d_in[15];  // b_f
  p.bias[3] = (const float*)d_in[17];  // b_u
  p.tWih = (const float*)d_in[18];
  p.tWhh = (const float*)d_in[19];
  p.tbih = (const float*)d_in[20];
  p.tbhh = (const float*)d_in[21];
  p.th0  = (const float*)d_in[22];
  p.tc0  = (const float*)d_in[23];

  float* ws = (float*)d_ws;
  size_t off = 0;
  p.stack = ws + off; off += (size_t)NB * SROWS * 1024;    // 33.5 MB
  p.tg    = ws + off; off += (size_t)NB * 256;             // 128 KB
  unsigned* barmem = (unsigned*)(ws + off); off += 4096;   // 16 KB
  p.wU = (f16*)(ws + off); off += (size_t)32 * 65536 / 2;  // 4 MB f16
  p.wT = (f16*)(ws + off); off += (size_t)32 * 25600 / 2;  // 1.6 MB f16
  if (off * sizeof(float) > ws_size) return;
  p.bm  = barmem;
  p.out = (float*)d_out;

  hipMemsetAsync(barmem, 0, 4096 * sizeof(unsigned), stream);

  void* args[] = { &p };
  hipError_t e = hipLaunchCooperativeKernel((void*)spinn_kernel, dim3(NWG), dim3(NTH),
                                            args, 0, stream);
  if (e != hipSuccess) {
    (void)hipGetLastError();
    spinn_kernel<<<dim3(NWG), dim3(NTH), 0, stream>>>(p);
  }
}

// Round 18
// 732.416 us; speedup vs baseline: 1.3333x; 1.3333x over previous
//
#include <hip/hip_runtime.h>

// SPINN v18 = v16 (MFMA champion, 736us) + fragment-major LDS operand layout
// ONLY (the isolated good half of v17: bank conflicts 8.3M -> 1.4M).
// opB[block][slot][8] f16, block = k>>3 per region (0-63 buf, 64-191 sp1|sp2,
// 192-199 th), slot = r XOR (block&15). B-frag ds_read_b128 = 16 contiguous
// slots = 256B per 16-lane quarter (2-way, free); staging writes one 8B store
// per float4 (XOR spreads banks). v17's provenance-split is DROPPED (it was
// the regression: extra sync, live acc across waits, 2x branchy code).

typedef _Float16 f16;
typedef f16 f16x8 __attribute__((ext_vector_type(8)));
typedef float f32x4 __attribute__((ext_vector_type(4)));

constexpr int NB  = 128;
constexpr int LL  = 32;
constexpr int TT  = 63;
constexpr int NWG = 256;
constexpr int NTH = 512;
constexpr int SROWS = 64;

struct Params {
  const float* seq; const int* trans;
  const float* Wx[4];              // i,o,f,u ; Wx[2]==W_o (ref bug kept)
  const float* Ul[4]; const float* Ur[4];
  const float* bias[4];            // b_i, b_o, b_f, b_u
  const float* tWih; const float* tWhh; const float* tbih; const float* tbhh;
  const float* th0; const float* tc0;
  float* stack; float* tg;
  f16* wU; f16* wT;
  unsigned* bm;
  float* out;
};

__device__ __forceinline__ float sigm(float x) { return 1.0f / (1.0f + __expf(-x)); }
__device__ __forceinline__ float tanh_f(float x) {
  x = fminf(fmaxf(x, -15.0f), 15.0f);
  float e = __expf(2.0f * x);
  return (e - 1.0f) / (e + 1.0f);
}
__device__ __forceinline__ float cohLoad(const float* a) {
  return __hip_atomic_load(const_cast<float*>(a), __ATOMIC_RELAXED, __HIP_MEMORY_SCOPE_AGENT);
}
__device__ __forceinline__ float4 cohLoad4(const float* a) {
  union { unsigned long long u[2]; float4 f; } r;
  const unsigned long long* p64 = (const unsigned long long*)a;
  r.u[0] = __hip_atomic_load(const_cast<unsigned long long*>(p64),
                             __ATOMIC_RELAXED, __HIP_MEMORY_SCOPE_AGENT);
  r.u[1] = __hip_atomic_load(const_cast<unsigned long long*>(p64 + 1),
                             __ATOMIC_RELAXED, __HIP_MEMORY_SCOPE_AGENT);
  return r.f;
}
__device__ __forceinline__ void cohStore(float* a, float v) {
  __hip_atomic_store(a, v, __ATOMIC_RELAXED, __HIP_MEMORY_SCOPE_AGENT);
}
__device__ __forceinline__ void cohStore2(float* a, float2 v) {
  union { float2 f; unsigned long long u; } r; r.f = v;
  __hip_atomic_store((unsigned long long*)a, r.u, __ATOMIC_RELAXED,
                     __HIP_MEMORY_SCOPE_AGENT);
}
__device__ __forceinline__ void drainvm() {
  asm volatile("s_waitcnt vmcnt(0)" ::: "memory");
}
__device__ __forceinline__ unsigned relAdd(unsigned* a) {
  return __hip_atomic_fetch_add(a, 1u, __ATOMIC_RELAXED, __HIP_MEMORY_SCOPE_AGENT) + 1u;
}
__device__ __forceinline__ void flagMax(unsigned* f, unsigned gen) {
  __hip_atomic_fetch_max(f, gen, __ATOMIC_RELAXED, __HIP_MEMORY_SCOPE_AGENT);
}
__device__ __forceinline__ void bar_arrive_any(unsigned* blk, unsigned gen, int l) {
  unsigned a = relAdd(blk + (l & 3) * 32);
  if (a == gen * 8u) {
    unsigned r = relAdd(blk + 128);
    if (r == gen * 4u) flagMax(blk + 160, gen);
  }
}
__device__ __forceinline__ void barA_arrive(unsigned* blk, unsigned gen, int l) {
  if (threadIdx.x == 0) bar_arrive_any(blk, gen, l);
}
__device__ __forceinline__ void bar_wait(unsigned* blk, unsigned gen) {
  if (threadIdx.x == 0) {
    while (__hip_atomic_load(blk + 160, __ATOMIC_RELAXED, __HIP_MEMORY_SCOPE_AGENT) < gen)
      __builtin_amdgcn_s_sleep(1);
  }
  __syncthreads();
}

__launch_bounds__(NTH)
__global__ void spinn_kernel(Params p) {
  const int w = blockIdx.x;
  const int t = threadIdx.x;
  const int cg  = w & 31;
  const int bgp = w >> 5;
  const int b0  = bgp * 16;
  const int nc0 = cg * 16;
  const int o0  = cg * 8;

  unsigned* blkA = p.bm + (size_t)bgp * 512;
  unsigned* blkB = blkA + 256;
  f16* wUcg = p.wU + (size_t)cg * 65536;   // [g][ks][lane][8]
  f16* wTcg = p.wT + (size_t)cg * 25600;   // [ks][lane][8]

  // fragment-major operand store: blocks 0-63 buf, 64-191 sp1|sp2, 192-199 th
  __shared__ f16   opB[200][16][8];
  __shared__ float th2s[16][68];
  __shared__ float tc2s[16][68];
  __shared__ float accR[64][17];
  __shared__ float xS[64][17];
  __shared__ float tbsum[256];
  __shared__ float biasS[4][16];
  __shared__ unsigned char sp1t[TT + 1][16], sp2t[TT + 1][16];
  __shared__ unsigned char buft[TT + 1][16], redt[TT + 1][16];
  __shared__ int anyredt[TT + 1];
  __shared__ int bufSamet[TT + 1];
  __shared__ unsigned char qstkS[16][40];

  const int rq = t >> 7;            // staging row quarter
  const int kb = (t & 127) * 4;     // staging float4 K offset

  auto wr4 = [&](int block, int r, float4 v) {
    union { f16 h[4]; uint2 u; } x;
    x.h[0] = (f16)v.x; x.h[1] = (f16)v.y; x.h[2] = (f16)v.z; x.h[3] = (f16)v.w;
    *(uint2*)&opB[block][r ^ (block & 15)][kb & 7] = x.u;
  };
  auto rdf = [&](int block, int m15) -> f16x8 {
    return *(const f16x8*)&opB[block][m15 ^ (block & 15)][0];
  };

  // ---- prologue: scalars / state
  if (t < 256) tbsum[t] = p.tbih[t] + p.tbhh[t];
  if (t < 64) biasS[t >> 4][t & 15] = p.bias[t >> 4][nc0 + (t & 15)];
  for (int i = t; i < 1024; i += NTH) {
    int b = i >> 6, j = i & 63;
    float h0 = p.th0[(size_t)(b0 + b) * 64 + j];
    th2s[b][j] = h0;
    tc2s[b][j] = p.tc0[(size_t)(b0 + b) * 64 + j];
    int blkTh = 192 + (j >> 3);
    opB[blkTh][b ^ (blkTh & 15)][j & 7] = (f16)h0;
  }
  // ---- prologue: weight conversion to f16 fragment order (own cg slice)
  for (int s = t; s < 8192; s += NTH) {             // tree: (g, ks, lane)
    int g = s >> 11, ks = (s >> 6) & 31, l = s & 63;
    int m = l & 15, hi = l >> 4;
    f16x8 v;
    #pragma unroll
    for (int i = 0; i < 8; ++i) {
      int k = ks * 32 + hi * 8 + i;
      const float* U = (k < 512) ? p.Ul[g] : p.Ur[g];
      v[i] = (f16)U[(size_t)(nc0 + m) * 512 + (k & 511)];
    }
    *(f16x8*)(wUcg + (size_t)s * 8) = v;
  }
  for (int s = t; s < 3200; s += NTH) {             // tracking: (ks, lane)
    int ks = s >> 6, l = s & 63;
    int m = l & 15, hi = l >> 4;
    f16x8 v = {(f16)0, (f16)0, (f16)0, (f16)0, (f16)0, (f16)0, (f16)0, (f16)0};
    if (m < 8) {
      int row = o0 + m;
      #pragma unroll
      for (int i = 0; i < 8; ++i) {
        int k = ks * 32 + hi * 8 + i;
        v[i] = (f16)((k < 1536) ? p.tWih[(size_t)row * 1536 + k]
                                : p.tWhh[(size_t)row * 64 + (k - 1536)]);
      }
    }
    *(f16x8*)(wTcg + (size_t)s * 8) = v;
  }
  // ---- prologue: schedule sim for our 16 b
  if (t < 16) {
    buft[0][t] = 255;
    int bl = t, qn = 0, bp = 0;
    for (int s = 1; s <= TT; ++s) {
      int mask = p.trans[(size_t)(b0 + bl) * TT + (s - 1)];
      int s1 = (qn >= 1) ? qstkS[bl][qn - 1] : 0;
      int s2 = (qn >= 2) ? qstkS[bl][qn - 2] : 0;
      int rd = (mask == 1);
      sp1t[s][bl] = (unsigned char)s1;
      sp2t[s][bl] = (unsigned char)s2;
      redt[s][bl] = (unsigned char)rd;
      buft[s][bl] = (unsigned char)((bp < LL) ? bp : LL);
      int qn2 = rd ? (qn - 2) : qn;
      qstkS[bl][qn2] = (unsigned char)s;
      qn = qn2 + 1;
      bp += rd ? 0 : 1;
    }
  }
  __syncthreads();
  if (t == 0) {
    for (int s = 1; s <= TT; ++s) {
      int a = 0, same = 1;
      for (int bl = 0; bl < 16; ++bl) {
        a |= redt[s][bl];
        same &= (buft[s][bl] == buft[s - 1][bl]);
      }
      anyredt[s] = a;
      bufSamet[s] = same;
    }
  }
  // zero our 32-col slice of stack row 0 for our 16 b
  {
    int bl = t >> 5, cc = t & 31;
    int col = (cc < 16) ? (nc0 + cc) : (512 + nc0 + (cc - 16));
    cohStore(p.stack + ((size_t)(b0 + bl) * SROWS) * 1024 + col, 0.0f);
  }
  drainvm();
  __syncthreads();
  unsigned genA = 1, genB = 0;
  barA_arrive(blkA, genA, cg);

  for (int step = 1; step <= TT; ++step) {
    const int anyred = anyredt[step];
    const unsigned gB = ++genB;
    const unsigned gAw = genA, gAn = genA + 1;

    // ---- pre-wait: seq staging (if buf changed), fp32 -> f16 fragment-major
    if (!bufSamet[step]) {
      #pragma unroll
      for (int i = 0; i < 4; ++i) {
        const int r = i * 4 + rq;
        const int bx = buft[step][r];
        float4 v = make_float4(0.f, 0.f, 0.f, 0.f);
        if (bx < LL) v = *(const float4*)(p.seq + ((size_t)(b0 + r) * LL + bx) * 1024 + kb);
        wr4(kb >> 3, r, v);
      }
    }
    // ---- pre-wait: shift steps write stack row from seq directly (fp32)
    if (!anyred && t < 128) {
      const int bl = t >> 3, nf = (t & 7) * 2, na = nc0 + nf;
      const int bx = buft[step][bl];
      float2 h2 = make_float2(0.f, 0.f), c2 = make_float2(0.f, 0.f);
      if (bx < LL) {
        const float* sb = p.seq + ((size_t)(b0 + bl) * LL + bx) * 1024;
        h2 = *(const float2*)(sb + na);
        c2 = *(const float2*)(sb + 512 + na);
      }
      float* sr = p.stack + ((size_t)(b0 + bl) * SROWS + step) * 1024;
      cohStore2(sr + na, h2);
      cohStore2(sr + 512 + na, c2);
    }
    float bhv = 0.f, bcv = 0.f, clv = 0.f, crv = 0.f;
    if (anyred && t < 256) {
      const int n = t & 15, bl = t >> 4, na = nc0 + n;
      int bx = buft[step][bl];
      if (bx < LL) {
        bhv = p.seq[((size_t)(b0 + bl) * LL + bx) * 1024 + na];
        bcv = p.seq[((size_t)(b0 + bl) * LL + bx) * 1024 + 512 + na];
      }
    }
    bar_wait(blkA, gAw);               // prev-step stack rows visible

    // ---- stack staging: cohLoad4 -> f16 fragment-major LDS
    {
      float4 v1r[4], v2r[4];
      #pragma unroll
      for (int i = 0; i < 4; ++i) {
        const int r = i * 4 + rq;
        v1r[i] = cohLoad4(p.stack + ((size_t)(b0 + r) * SROWS + sp1t[step][r]) * 1024 + kb);
        v2r[i] = cohLoad4(p.stack + ((size_t)(b0 + r) * SROWS + sp2t[step][r]) * 1024 + kb);
      }
      #pragma unroll
      for (int i = 0; i < 4; ++i) {
        const int r = i * 4 + rq;
        wr4(64 + (kb >> 3), r, v1r[i]);
        wr4(128 + (kb >> 3), r, v2r[i]);
      }
    }
    if (anyred && t < 256) {
      const int n = t & 15, bl = t >> 4, na = nc0 + n;
      clv = cohLoad(p.stack + ((size_t)(b0 + bl) * SROWS + sp1t[step][bl]) * 1024 + 512 + na);
      crv = cohLoad(p.stack + ((size_t)(b0 + bl) * SROWS + sp2t[step][bl]) * 1024 + 512 + na);
    }
    if (!anyred) drainvm();
    __syncthreads();
    if (!anyred) barA_arrive(blkA, gAn, cg);   // EARLY (after wait: safe)

    // ---- compute: tree MFMA on waves 0-3 || tracking MFMA on wave 7
    if (t < 256) {
      if (anyred) {
        const int g = t >> 6;            // M-tile = gate
        const int lane = t & 63;
        const int m15 = lane & 15, hi = lane >> 4;
        const f16* aBase = wUcg + (size_t)g * 32 * 512;
        f32x4 acc = {0.f, 0.f, 0.f, 0.f};
        #pragma unroll 4
        for (int ks = 0; ks < 32; ++ks) {
          f16x8 a = *(const f16x8*)(aBase + ((size_t)ks * 64 + lane) * 8);
          acc = __builtin_amdgcn_mfma_f32_16x16x32_f16(a, rdf(64 + ks * 4 + hi, m15), acc, 0, 0, 0);
        }
        #pragma unroll
        for (int r = 0; r < 4; ++r)
          accR[g * 16 + hi * 4 + r][m15] = acc[r];
      }
    } else if (t >= 448) {
      const int lane = t & 63;
      const int m15 = lane & 15, hi = lane >> 4;
      f32x4 acc = {0.f, 0.f, 0.f, 0.f};
      #pragma unroll 2
      for (int ks = 0; ks < 48; ++ks) {
        f16x8 a = *(const f16x8*)(wTcg + ((size_t)ks * 64 + lane) * 8);
        acc = __builtin_amdgcn_mfma_f32_16x16x32_f16(a, rdf(ks * 4 + hi, m15), acc, 0, 0, 0);
      }
      #pragma unroll
      for (int ks = 48; ks < 50; ++ks) {
        f16x8 a = *(const f16x8*)(wTcg + ((size_t)ks * 64 + lane) * 8);
        acc = __builtin_amdgcn_mfma_f32_16x16x32_f16(a, rdf(192 + (ks - 48) * 4 + hi, m15), acc, 0, 0, 0);
      }
      if (hi < 2) {
        #pragma unroll
        for (int r = 0; r < 4; ++r)
          cohStore(p.tg + (size_t)(b0 + m15) * 256 + o0 + hi * 4 + r, acc[r]);
      }
      drainvm();                         // wave-level: tg stores -> IC
      if (lane == 0) bar_arrive_any(blkB, gB, cg);   // EARLY per-WG arrival
    }
    bar_wait(blkB, gB);                  // tg of whole set visible

    // ---- tracking LSTM elementwise (16 b x 64 j; tg loads up-front)
    {
      float gi[2], gf[2], gg[2], go[2];
      int bbp[2], jjp[2];
      #pragma unroll
      for (int rep = 0; rep < 2; ++rep) {
        const int it = t + rep * 512;
        bbp[rep] = it >> 6; jjp[rep] = it & 63;
        const float* tgb = p.tg + (size_t)(b0 + bbp[rep]) * 256;
        gi[rep] = cohLoad(tgb + jjp[rep]);
        gf[rep] = cohLoad(tgb + 64 + jjp[rep]);
        gg[rep] = cohLoad(tgb + 128 + jjp[rep]);
        go[rep] = cohLoad(tgb + 192 + jjp[rep]);
      }
      #pragma unroll
      for (int rep = 0; rep < 2; ++rep) {
        const int b = bbp[rep], j = jjp[rep];
        float c2 = sigm(gf[rep] + tbsum[64 + j]) * tc2s[b][j]
                 + sigm(gi[rep] + tbsum[j]) * tanh_f(gg[rep] + tbsum[128 + j]);
        float h2 = sigm(go[rep] + tbsum[192 + j]) * tanh_f(c2);
        tc2s[b][j] = c2;
        th2s[b][j] = h2;
        int blkTh = 192 + (j >> 3);
        opB[blkTh][b ^ (blkTh & 15)][j & 7] = (f16)h2;
      }
    }
    if (anyred) {
      __syncthreads();
      // x@W: 64 cc x 16 b, K=64 (fp32 VALU, weights L2-hot)
      #pragma unroll
      for (int rep = 0; rep < 2; ++rep) {
        const int it = t + rep * 512;
        const int cc = it >> 4, bl = it & 15;
        const float* wr = p.Wx[cc >> 4] + (size_t)(nc0 + (cc & 15)) * 64;
        float x = 0.f;
        #pragma unroll 4
        for (int j4 = 0; j4 < 64; j4 += 4) {
          float4 wv = *(const float4*)(wr + j4);
          float4 xv = *(const float4*)&th2s[bl][j4];
          x += wv.x*xv.x + wv.y*xv.y + wv.z*xv.z + wv.w*xv.w;
        }
        xS[cc][bl] = x;
      }
      __syncthreads();
      // gates + stack row write
      if (t < 256) {
        const int n = t & 15, bl = t >> 4, na = nc0 + n;
        float h, c;
        if (redt[step][bl]) {
          float pre[4];
          #pragma unroll
          for (int g = 0; g < 4; ++g) {
            const int cc = g * 16 + n;
            pre[g] = accR[cc][bl] + xS[cc][bl] + biasS[g][n];
          }
          float iv = sigm(pre[0]), ov = sigm(pre[1]);
          float fv = sigm(pre[2]), uv = tanh_f(pre[3]);
          c = iv * uv + fv * (clv + crv);
          h = ov * tanh_f(c);
        } else { h = bhv; c = bcv; }
        float* sr = p.stack + ((size_t)(b0 + bl) * SROWS + step) * 1024;
        cohStore(sr + na, h);
        cohStore(sr + 512 + na, c);
        if (step == TT) p.out[(size_t)(b0 + bl) * 512 + na] = h;
        drainvm();
      }
      __syncthreads();
      barA_arrive(blkA, gAn, cg);
    }
    genA = gAn;
  }
}

extern "C" void kernel_launch(void* const* d_in, const int* in_sizes, int n_in,
                              void* d_out, int out_size, void* d_ws, size_t ws_size,
                              hipStream_t stream) {
  Params p;
  p.seq   = (const float*)d_in[0];
  p.trans = (const int*)d_in[1];
  p.Wx[0] = (const float*)d_in[2];   // W_i
  p.Wx[1] = (const float*)d_in[4];   // W_o
  p.Wx[2] = (const float*)d_in[4];   // W_o  (ref bug: f-gate uses W_o)
  p.Wx[3] = (const float*)d_in[5];   // W_u
  p.Ul[0] = (const float*)d_in[6];  p.Ur[0] = (const float*)d_in[7];    // i
  p.Ul[1] = (const float*)d_in[10]; p.Ur[1] = (const float*)d_in[11];   // o
  p.Ul[2] = (const float*)d_in[8];  p.Ur[2] = (const float*)d_in[9];    // f
  p.Ul[3] = (const float*)d_in[12]; p.Ur[3] = (const float*)d_in[13];   // u
  p.bias[0] = (const float*)d_in[14];  // b_i
  p.bias[1] = (const float*)d_in[16];  // b_o
  p.bias[2] = (const float*)d_in[15];  // b_f
  p.bias[3] = (const float*)d_in[17];  // b_u
  p.tWih = (const float*)d_in[18];
  p.tWhh = (const float*)d_in[19];
  p.tbih = (const float*)d_in[20];
  p.tbhh = (const float*)d_in[21];
  p.th0  = (const float*)d_in[22];
  p.tc0  = (const float*)d_in[23];

  float* ws = (float*)d_ws;
  size_t off = 0;
  p.stack = ws + off; off += (size_t)NB * SROWS * 1024;    // 33.5 MB
  p.tg    = ws + off; off += (size_t)NB * 256;             // 128 KB
  unsigned* barmem = (unsigned*)(ws + off); off += 4096;   // 16 KB
  p.wU = (f16*)(ws + off); off += (size_t)32 * 65536 / 2;  // 4 MB f16
  p.wT = (f16*)(ws + off); off += (size_t)32 * 25600 / 2;  // 1.6 MB f16
  if (off * sizeof(float) > ws_size) return;
  p.bm  = barmem;
  p.out = (float*)d_out;

  hipMemsetAsync(barmem, 0, 4096 * sizeof(unsigned), stream);

  void* args[] = { &p };
  hipError_t e = hipLaunchCooperativeKernel((void*)spinn_kernel, dim3(NWG), dim3(NTH),
                                            args, 0, stream);
  if (e != hipSuccess) {
    (void)hipGetLastError();
    spinn_kernel<<<dim3(NWG), dim3(NTH), 0, stream>>>(p);
  }
}